// Round 4
// baseline (567.354 us; speedup 1.0000x reference)
//
#include <hip/hip_runtime.h>
#include <hip/hip_bf16.h>

#define NFEAT 128
typedef unsigned int uint;
typedef unsigned short ushort;

__device__ __forceinline__ uint f2bf(float f) {  // RNE float->bf16 (finite values)
    uint x = __float_as_uint(f);
    return (x + 0x7fffu + ((x >> 16) & 1u)) >> 16;
}

// ---------------- int64-vs-int32 detection + canonicalization ----------------

__global__ __launch_bounds__(256) void k_detect(const int* __restrict__ p, int nElem,
                                                int* __restrict__ flag) {
    __shared__ int any;
    int t = threadIdx.x;
    if (t == 0) any = 0;
    __syncthreads();
    long long stride = (long long)nElem / 512;
    if (stride < 1) stride = 1;
    long long pos = 2 * ((long long)t * stride) + 1;
    if (pos < nElem && p[pos] != 0) atomicOr(&any, 1);
    __syncthreads();
    if (t == 0) *flag = any ? 0 : 1;
}

__global__ __launch_bounds__(256) void k_cvt(const void* __restrict__ src, int* __restrict__ dst,
                                             int n, const int* __restrict__ flag) {
    int i = blockIdx.x * 256 + threadIdx.x;
    if (i < n) {
        if (*flag)
            dst[i] = (int)((const long long*)src)[i];
        else
            dst[i] = ((const int*)src)[i];
    }
}

// ---------------- CSR build ----------------

__global__ __launch_bounds__(256) void k_init_cnt(int* __restrict__ cnt, int N) {
    int i = blockIdx.x * 256 + threadIdx.x;
    if (i < N) cnt[i] = 1;  // self-loop
}

__global__ __launch_bounds__(256) void k_count(const int* __restrict__ col, int* __restrict__ cnt, int E) {
    int e = blockIdx.x * 256 + threadIdx.x;
    if (e < E) atomicAdd(&cnt[col[e]], 1);
}

__global__ __launch_bounds__(256) void k_scan1(const int* __restrict__ cnt, int* __restrict__ pre,
                                               int* __restrict__ bsum, int N) {
    __shared__ int s[256];
    int tid = threadIdx.x;
    int gid = blockIdx.x * 256 + tid;
    int v = (gid < N) ? cnt[gid] : 0;
    s[tid] = v;
    __syncthreads();
    for (int off = 1; off < 256; off <<= 1) {
        int t = (tid >= off) ? s[tid - off] : 0;
        __syncthreads();
        s[tid] += t;
        __syncthreads();
    }
    if (gid < N) pre[gid] = s[tid] - v;  // exclusive within block
    if (tid == 255) bsum[blockIdx.x] = s[255];
}

__global__ __launch_bounds__(256) void k_scan2(int* __restrict__ bsum, int NB) {
    __shared__ int s[256];
    int tid = threadIdx.x;
    int v = (tid < NB) ? bsum[tid] : 0;
    s[tid] = v;
    __syncthreads();
    for (int off = 1; off < 256; off <<= 1) {
        int t = (tid >= off) ? s[tid - off] : 0;
        __syncthreads();
        s[tid] += t;
        __syncthreads();
    }
    if (tid < NB) bsum[tid] = s[tid] - v;  // exclusive block offsets
}

__global__ __launch_bounds__(256) void k_scan3(const int* __restrict__ cnt, const int* __restrict__ pre,
                                               const int* __restrict__ bsum, int* __restrict__ row_ptr,
                                               int* __restrict__ cursor, float* __restrict__ dinv,
                                               int N, int total) {
    int i = blockIdx.x * 256 + threadIdx.x;
    if (i < N) {
        int base = pre[i] + bsum[blockIdx.x];
        row_ptr[i] = base;
        cursor[i] = base;
        dinv[i] = rsqrtf((float)cnt[i]);  // deg >= 1 always (self-loop)
    }
    if (i == 0) row_ptr[N] = total;
}

__global__ __launch_bounds__(256) void k_fill(const int* __restrict__ eidx, const float* __restrict__ dinv,
                                              int* __restrict__ cursor, int2* __restrict__ csr,
                                              int E, int N) {
    int t = blockIdx.x * 256 + threadIdx.x;
    if (t < E) {
        int src = eidx[t];
        int dst = eidx[E + t];
        int pos = atomicAdd(&cursor[dst], 1);
        float nrm = dinv[src] * dinv[dst];
        csr[pos] = make_int2(src, __float_as_int(nrm));
    } else if (t < E + N) {
        int i = t - E;
        int pos = atomicAdd(&cursor[i], 1);
        float d = dinv[i];
        csr[pos] = make_int2(i, __float_as_int(d * d));
    }
}

// ---------------- GEMM: C_bf16[M,128] = A[M,128] @ W_f32[128,128] ----------------
// K-tiled: 256 threads, 64 rows x 128 cols/block, K in 4 steps of 32.
// A (fp32 for layer0, bf16 for layers 1-2) staged transposed into fp32 LDS;
// W staged fp32 (no rounding of W anywhere). Accumulate fp32, store bf16.

template <bool BF16IN>
__global__ __launch_bounds__(256) void k_gemm(const void* __restrict__ Ain, const float* __restrict__ W,
                                              uint* __restrict__ C, int M) {
    __shared__ float AT[32 * 64];    // [k][row]
    __shared__ float Wld[32 * 128];  // [k][col]
    int tid = threadIdx.x;
    int tx = tid & 15;
    int ty = tid >> 4;
    int row0 = blockIdx.x * 64;
    const float4* W4 = (const float4*)W;

    float acc[4][8] = {};
    int srow = tid >> 2;       // 0..63: staging row
    int q0 = 2 * (tid & 3);    // 0,2,4,6
    int rs = row0 + srow;
    bool rv = rs < M;

#pragma unroll 1
    for (int s = 0; s < 4; ++s) {
        __syncthreads();  // previous iteration's LDS reads done
        float av8[8];
        if (BF16IN) {
            uint4 v = rv ? *(const uint4*)((const ushort*)Ain + (size_t)rs * NFEAT + s * 32 + q0 * 4)
                         : make_uint4(0u, 0u, 0u, 0u);
            uint u[4] = {v.x, v.y, v.z, v.w};
#pragma unroll
            for (int m = 0; m < 4; ++m) {
                av8[2 * m]     = __uint_as_float(u[m] << 16);
                av8[2 * m + 1] = __uint_as_float(u[m] & 0xffff0000u);
            }
        } else {
            const float4* A4 = (const float4*)Ain;
            float4 va = rv ? A4[(size_t)rs * 32 + s * 8 + q0]     : make_float4(0.f, 0.f, 0.f, 0.f);
            float4 vb = rv ? A4[(size_t)rs * 32 + s * 8 + q0 + 1] : make_float4(0.f, 0.f, 0.f, 0.f);
            av8[0] = va.x; av8[1] = va.y; av8[2] = va.z; av8[3] = va.w;
            av8[4] = vb.x; av8[5] = vb.y; av8[6] = vb.z; av8[7] = vb.w;
        }
#pragma unroll
        for (int m = 0; m < 8; ++m) AT[(q0 * 4 + m) * 64 + srow] = av8[m];
#pragma unroll
        for (int i = 0; i < 4; ++i) {
            int idx = tid + 256 * i;  // 1024 float4s = W[32][128] tile
            ((float4*)Wld)[idx] = W4[(size_t)(s * 32 + (idx >> 5)) * 32 + (idx & 31)];
        }
        __syncthreads();
#pragma unroll 4
        for (int kk = 0; kk < 32; ++kk) {
            float4 a  = *(const float4*)&AT[kk * 64 + ty * 4];
            float4 w0 = *(const float4*)&Wld[kk * 128 + tx * 4];
            float4 w1 = *(const float4*)&Wld[kk * 128 + 64 + tx * 4];
            float av[4] = {a.x, a.y, a.z, a.w};
            float wv[8] = {w0.x, w0.y, w0.z, w0.w, w1.x, w1.y, w1.z, w1.w};
#pragma unroll
            for (int i = 0; i < 4; ++i)
#pragma unroll
                for (int j = 0; j < 8; ++j)
                    acc[i][j] = fmaf(av[i], wv[j], acc[i][j]);
        }
    }
#pragma unroll
    for (int i = 0; i < 4; ++i) {
        int r = row0 + ty * 4 + i;
        if (r < M) {
            uint* Crow = C + (size_t)r * 64;
            uint2 o;
            o.x = f2bf(acc[i][0]) | (f2bf(acc[i][1]) << 16);
            o.y = f2bf(acc[i][2]) | (f2bf(acc[i][3]) << 16);
            *(uint2*)&Crow[tx * 2] = o;
            o.x = f2bf(acc[i][4]) | (f2bf(acc[i][5]) << 16);
            o.y = f2bf(acc[i][6]) | (f2bf(acc[i][7]) << 16);
            *(uint2*)&Crow[32 + tx * 2] = o;
        }
    }
}

// ---------------- gather aggregation: wave per destination node (bf16 rows) ----------------
// lane handles feature columns {2*lane, 2*lane+1}; one uint load per edge per lane
// = 256 B per gathered row per wave. Accumulate fp32, store packed bf16.

__global__ __launch_bounds__(256) void k_aggregate(const uint* __restrict__ hw, const int2* __restrict__ csr,
                                                   const int* __restrict__ row_ptr, const float* __restrict__ bias,
                                                   uint* __restrict__ hout, int N) {
    int wid = (blockIdx.x * 256 + threadIdx.x) >> 6;
    int lane = threadIdx.x & 63;
    if (wid >= N) return;
    int beg = row_ptr[wid];
    int end = row_ptr[wid + 1];
    float a0 = 0.f, a1 = 0.f;
    for (int e = beg; e < end; ++e) {
        int2 me = csr[e];
        float nrm = __int_as_float(me.y);
        uint v = hw[(size_t)me.x * 64 + lane];
        a0 = fmaf(nrm, __uint_as_float(v << 16), a0);
        a1 = fmaf(nrm, __uint_as_float(v & 0xffff0000u), a1);
    }
    float2 bb = *(const float2*)&bias[2 * lane];
    a0 = fmaxf(a0 + bb.x, 0.f);
    a1 = fmaxf(a1 + bb.y, 0.f);
    hout[(size_t)wid * 64 + lane] = f2bf(a0) | (f2bf(a1) << 16);
}

// ---------------- pooling: block(64) per graph (batch sorted); bf16 input ----------------

__global__ __launch_bounds__(64) void k_pool(const uint* __restrict__ h, const int* __restrict__ batch,
                                             float* __restrict__ pooled, int N) {
    int g = blockIdx.x;
    int t = threadIdx.x;
    int lo = 0, hi = N;
    while (lo < hi) { int mid = (lo + hi) >> 1; if (batch[mid] < g) lo = mid + 1; else hi = mid; }
    int s = lo;
    hi = N;
    while (lo < hi) { int mid = (lo + hi) >> 1; if (batch[mid] < g + 1) lo = mid + 1; else hi = mid; }
    int e = lo;
    float a0 = 0.f, a1 = 0.f;
    for (int n = s; n < e; ++n) {
        uint v = h[(size_t)n * 64 + t];
        a0 += __uint_as_float(v << 16);
        a1 += __uint_as_float(v & 0xffff0000u);
    }
    pooled[g * NFEAT + 2 * t]     = a0;
    pooled[g * NFEAT + 2 * t + 1] = a1;
}

// ---------------- head: out[g,c] = pooled[g,:] @ W_out[:,c] + b_out[c] (fp32 out) ----------------

__global__ __launch_bounds__(64) void k_head(const float* __restrict__ pooled, const float* __restrict__ Wout,
                                             const float* __restrict__ bout, float* __restrict__ out) {
    int g = blockIdx.x;
    int l = threadIdx.x;
    float p0 = pooled[g * NFEAT + l];
    float p1 = pooled[g * NFEAT + 64 + l];
#pragma unroll
    for (int c = 0; c < 10; ++c) {
        float v = fmaf(p0, Wout[l * 10 + c], p1 * Wout[(64 + l) * 10 + c]);
#pragma unroll
        for (int off = 32; off > 0; off >>= 1) v += __shfl_down(v, off);
        if (l == 0) out[g * 10 + c] = v + bout[c];
    }
}

// ---------------- launch ----------------

extern "C" void kernel_launch(void* const* d_in, const int* in_sizes, int n_in,
                              void* d_out, int out_size, void* d_ws, size_t ws_size,
                              hipStream_t stream) {
    const float* x         = (const float*)d_in[0];
    const void*  eidx_raw  = d_in[1];
    const void*  batch_raw = d_in[2];
    const float* W         = (const float*)d_in[3];
    const float* bias      = (const float*)d_in[4];
    const float* Wout      = (const float*)d_in[5];
    const float* bout      = (const float*)d_in[6];

    int N = in_sizes[0] / NFEAT;   // 50000
    int E = in_sizes[1] / 2;       // 800000
    int NG = out_size / 10;        // 512

    char* ws = (char*)d_ws;
    auto alloc = [&](size_t bytes) {
        char* p = ws;
        ws += (bytes + 255) & ~(size_t)255;
        return p;
    };
    uint*  hw      = (uint*)alloc((size_t)N * NFEAT * 2);   // bf16 activations
    uint*  hbuf    = (uint*)alloc((size_t)N * NFEAT * 2);   // bf16 activations
    int2*  csr     = (int2*)alloc((size_t)(E + N) * 8);
    int*   cnt     = (int*)alloc((size_t)N * 4);
    int*   pre     = (int*)alloc((size_t)N * 4);
    int*   bsum    = (int*)alloc(1024);
    int*   row_ptr = (int*)alloc((size_t)(N + 1) * 4);
    int*   cursor  = (int*)alloc((size_t)N * 4);
    float* dinv    = (float*)alloc((size_t)N * 4);
    float* pooled  = (float*)alloc((size_t)NG * NFEAT * 4);
    int*   eidx32  = (int*)alloc((size_t)2 * E * 4);
    int*   batch32 = (int*)alloc((size_t)N * 4);
    int*   flags   = (int*)alloc(256);

    // canonicalize possibly-int64 index inputs to int32
    k_detect<<<1, 256, 0, stream>>>((const int*)eidx_raw, 2 * E, &flags[0]);
    k_detect<<<1, 256, 0, stream>>>((const int*)batch_raw, N, &flags[1]);
    k_cvt<<<(2 * E + 255) / 256, 256, 0, stream>>>(eidx_raw, eidx32, 2 * E, &flags[0]);
    k_cvt<<<(N + 255) / 256, 256, 0, stream>>>(batch_raw, batch32, N, &flags[1]);

    int nbN = (N + 255) / 256;  // 196 <= 256 so scan2 single block works

    k_init_cnt<<<nbN, 256, 0, stream>>>(cnt, N);
    k_count<<<(E + 255) / 256, 256, 0, stream>>>(eidx32 + E, cnt, E);
    k_scan1<<<nbN, 256, 0, stream>>>(cnt, pre, bsum, N);
    k_scan2<<<1, 256, 0, stream>>>(bsum, nbN);
    k_scan3<<<nbN, 256, 0, stream>>>(cnt, pre, bsum, row_ptr, cursor, dinv, N, E + N);
    k_fill<<<(E + N + 255) / 256, 256, 0, stream>>>(eidx32, dinv, cursor, csr, E, N);

    for (int l = 0; l < 3; ++l) {
        const float* Wl = W + (size_t)l * NFEAT * NFEAT;
        if (l == 0)
            k_gemm<false><<<(N + 63) / 64, 256, 0, stream>>>(x, Wl, hw, N);
        else
            k_gemm<true><<<(N + 63) / 64, 256, 0, stream>>>(hbuf, Wl, hw, N);
        k_aggregate<<<(N * 64 + 255) / 256, 256, 0, stream>>>(hw, csr, row_ptr, bias + (size_t)l * NFEAT, hbuf, N);
    }

    k_pool<<<NG, 64, 0, stream>>>(hbuf, batch32, pooled, N);
    k_head<<<NG, 64, 0, stream>>>(pooled, Wout, bout, (float*)d_out);
}

// Round 5
// 402.504 us; speedup vs baseline: 1.4096x; 1.4096x over previous
//
#include <hip/hip_runtime.h>
#include <hip/hip_bf16.h>

#define NFEAT 128
typedef unsigned int uint;
typedef unsigned short ushort;

__device__ __forceinline__ uint f2bf(float f) {  // RNE float->bf16 (finite values)
    uint x = __float_as_uint(f);
    return (x + 0x7fffu + ((x >> 16) & 1u)) >> 16;
}

// ---------------- int64-vs-int32 detection + canonicalization ----------------

__global__ __launch_bounds__(256) void k_detect(const int* __restrict__ p, int nElem,
                                                int* __restrict__ flag) {
    __shared__ int any;
    int t = threadIdx.x;
    if (t == 0) any = 0;
    __syncthreads();
    long long stride = (long long)nElem / 512;
    if (stride < 1) stride = 1;
    long long pos = 2 * ((long long)t * stride) + 1;
    if (pos < nElem && p[pos] != 0) atomicOr(&any, 1);
    __syncthreads();
    if (t == 0) *flag = any ? 0 : 1;
}

__global__ __launch_bounds__(256) void k_cvt(const void* __restrict__ src, int* __restrict__ dst,
                                             int n, const int* __restrict__ flag) {
    int i = blockIdx.x * 256 + threadIdx.x;
    if (i < n) {
        if (*flag)
            dst[i] = (int)((const long long*)src)[i];
        else
            dst[i] = ((const int*)src)[i];
    }
}

// ---------------- CSR build ----------------

__global__ __launch_bounds__(256) void k_init_cnt(int* __restrict__ cnt, int N) {
    int i = blockIdx.x * 256 + threadIdx.x;
    if (i < N) cnt[i] = 1;  // self-loop
}

__global__ __launch_bounds__(256) void k_count(const int* __restrict__ col, int* __restrict__ cnt, int E) {
    int e = blockIdx.x * 256 + threadIdx.x;
    if (e < E) atomicAdd(&cnt[col[e]], 1);
}

__global__ __launch_bounds__(256) void k_scan1(const int* __restrict__ cnt, int* __restrict__ pre,
                                               int* __restrict__ bsum, int N) {
    __shared__ int s[256];
    int tid = threadIdx.x;
    int gid = blockIdx.x * 256 + tid;
    int v = (gid < N) ? cnt[gid] : 0;
    s[tid] = v;
    __syncthreads();
    for (int off = 1; off < 256; off <<= 1) {
        int t = (tid >= off) ? s[tid - off] : 0;
        __syncthreads();
        s[tid] += t;
        __syncthreads();
    }
    if (gid < N) pre[gid] = s[tid] - v;  // exclusive within block
    if (tid == 255) bsum[blockIdx.x] = s[255];
}

__global__ __launch_bounds__(256) void k_scan2(int* __restrict__ bsum, int NB) {
    __shared__ int s[256];
    int tid = threadIdx.x;
    int v = (tid < NB) ? bsum[tid] : 0;
    s[tid] = v;
    __syncthreads();
    for (int off = 1; off < 256; off <<= 1) {
        int t = (tid >= off) ? s[tid - off] : 0;
        __syncthreads();
        s[tid] += t;
        __syncthreads();
    }
    if (tid < NB) bsum[tid] = s[tid] - v;  // exclusive block offsets
}

__global__ __launch_bounds__(256) void k_scan3(const int* __restrict__ cnt, const int* __restrict__ pre,
                                               const int* __restrict__ bsum, int* __restrict__ row_ptr,
                                               int* __restrict__ cursor, float* __restrict__ dinv,
                                               int N, int total) {
    int i = blockIdx.x * 256 + threadIdx.x;
    if (i < N) {
        int base = pre[i] + bsum[blockIdx.x];
        row_ptr[i] = base;
        cursor[i] = base;
        dinv[i] = rsqrtf((float)cnt[i]);  // deg >= 1 always (self-loop)
    }
    if (i == 0) row_ptr[N] = total;
}

__global__ __launch_bounds__(256) void k_fill(const int* __restrict__ eidx, const float* __restrict__ dinv,
                                              int* __restrict__ cursor, int2* __restrict__ csr,
                                              int E, int N) {
    int t = blockIdx.x * 256 + threadIdx.x;
    if (t < E) {
        int src = eidx[t];
        int dst = eidx[E + t];
        int pos = atomicAdd(&cursor[dst], 1);
        float nrm = dinv[src] * dinv[dst];
        csr[pos] = make_int2(src, __float_as_int(nrm));
    } else if (t < E + N) {
        int i = t - E;
        int pos = atomicAdd(&cursor[i], 1);
        float d = dinv[i];
        csr[pos] = make_int2(i, __float_as_int(d * d));
    }
}

// ---------------- GEMM: C_bf16[M,128] = A[M,128] @ W_f32[128,128] ----------------

template <bool BF16IN>
__global__ __launch_bounds__(256) void k_gemm(const void* __restrict__ Ain, const float* __restrict__ W,
                                              uint* __restrict__ C, int M) {
    __shared__ float AT[32 * 64];    // [k][row]
    __shared__ float Wld[32 * 128];  // [k][col]
    int tid = threadIdx.x;
    int tx = tid & 15;
    int ty = tid >> 4;
    int row0 = blockIdx.x * 64;
    const float4* W4 = (const float4*)W;

    float acc[4][8] = {};
    int srow = tid >> 2;       // 0..63: staging row
    int q0 = 2 * (tid & 3);    // 0,2,4,6
    int rs = row0 + srow;
    bool rv = rs < M;

#pragma unroll 1
    for (int s = 0; s < 4; ++s) {
        __syncthreads();  // previous iteration's LDS reads done
        float av8[8];
        if (BF16IN) {
            uint4 v = rv ? *(const uint4*)((const ushort*)Ain + (size_t)rs * NFEAT + s * 32 + q0 * 4)
                         : make_uint4(0u, 0u, 0u, 0u);
            uint u[4] = {v.x, v.y, v.z, v.w};
#pragma unroll
            for (int m = 0; m < 4; ++m) {
                av8[2 * m]     = __uint_as_float(u[m] << 16);
                av8[2 * m + 1] = __uint_as_float(u[m] & 0xffff0000u);
            }
        } else {
            const float4* A4 = (const float4*)Ain;
            float4 va = rv ? A4[(size_t)rs * 32 + s * 8 + q0]     : make_float4(0.f, 0.f, 0.f, 0.f);
            float4 vb = rv ? A4[(size_t)rs * 32 + s * 8 + q0 + 1] : make_float4(0.f, 0.f, 0.f, 0.f);
            av8[0] = va.x; av8[1] = va.y; av8[2] = va.z; av8[3] = va.w;
            av8[4] = vb.x; av8[5] = vb.y; av8[6] = vb.z; av8[7] = vb.w;
        }
#pragma unroll
        for (int m = 0; m < 8; ++m) AT[(q0 * 4 + m) * 64 + srow] = av8[m];
#pragma unroll
        for (int i = 0; i < 4; ++i) {
            int idx = tid + 256 * i;  // 1024 float4s = W[32][128] tile
            ((float4*)Wld)[idx] = W4[(size_t)(s * 32 + (idx >> 5)) * 32 + (idx & 31)];
        }
        __syncthreads();
#pragma unroll 4
        for (int kk = 0; kk < 32; ++kk) {
            float4 a  = *(const float4*)&AT[kk * 64 + ty * 4];
            float4 w0 = *(const float4*)&Wld[kk * 128 + tx * 4];
            float4 w1 = *(const float4*)&Wld[kk * 128 + 64 + tx * 4];
            float av[4] = {a.x, a.y, a.z, a.w};
            float wv[8] = {w0.x, w0.y, w0.z, w0.w, w1.x, w1.y, w1.z, w1.w};
#pragma unroll
            for (int i = 0; i < 4; ++i)
#pragma unroll
                for (int j = 0; j < 8; ++j)
                    acc[i][j] = fmaf(av[i], wv[j], acc[i][j]);
        }
    }
#pragma unroll
    for (int i = 0; i < 4; ++i) {
        int r = row0 + ty * 4 + i;
        if (r < M) {
            uint* Crow = C + (size_t)r * 64;
            uint2 o;
            o.x = f2bf(acc[i][0]) | (f2bf(acc[i][1]) << 16);
            o.y = f2bf(acc[i][2]) | (f2bf(acc[i][3]) << 16);
            *(uint2*)&Crow[tx * 2] = o;
            o.x = f2bf(acc[i][4]) | (f2bf(acc[i][5]) << 16);
            o.y = f2bf(acc[i][6]) | (f2bf(acc[i][7]) << 16);
            *(uint2*)&Crow[32 + tx * 2] = o;
        }
    }
}

// ---------------- gather aggregation v2: wave per node, batched edge loads ----------------
// v1 was latency-bound (86 us, HBM 14%): dependent chain csr[e] -> hw row per edge.
// v2: lane l vector-loads csr[base+l] (64 entries in one instruction), then
// __shfl-broadcasts each entry; row loads hand-unrolled x8 so 8 independent
// global_load_dwords are in flight per wait. Latency exposure ~1 per 64 edges.

__global__ __launch_bounds__(256) void k_aggregate(const uint* __restrict__ hw, const int2* __restrict__ csr,
                                                   const int* __restrict__ row_ptr, const float* __restrict__ bias,
                                                   uint* __restrict__ hout, int N) {
    int wid = (blockIdx.x * 256 + threadIdx.x) >> 6;
    int lane = threadIdx.x & 63;
    if (wid >= N) return;
    int beg = row_ptr[wid];
    int end = row_ptr[wid + 1];
    float a0 = 0.f, a1 = 0.f;
    for (int base = beg; base < end; base += 64) {
        int n = end - base;
        if (n > 64) n = 64;
        int2 me = csr[base + (lane < n ? lane : n - 1)];
        int j = 0;
        for (; j + 8 <= n; j += 8) {
            uint v[8];
            float nr[8];
#pragma unroll
            for (int u = 0; u < 8; ++u) {
                int src = __shfl(me.x, j + u);
                nr[u] = __int_as_float(__shfl(me.y, j + u));
                v[u] = hw[(size_t)src * 64 + lane];
            }
#pragma unroll
            for (int u = 0; u < 8; ++u) {
                a0 = fmaf(nr[u], __uint_as_float(v[u] << 16), a0);
                a1 = fmaf(nr[u], __uint_as_float(v[u] & 0xffff0000u), a1);
            }
        }
        if (j < n) {
            uint v[8];
            float nr[8];
            int m = n - j;  // 1..7
#pragma unroll
            for (int u = 0; u < 8; ++u) {
                int jj = j + (u < m ? u : m - 1);  // clamp: valid lane, dup loads
                int src = __shfl(me.x, jj);
                nr[u] = (u < m) ? __int_as_float(__shfl(me.y, jj)) : 0.f;
                v[u] = hw[(size_t)src * 64 + lane];
            }
#pragma unroll
            for (int u = 0; u < 8; ++u) {
                a0 = fmaf(nr[u], __uint_as_float(v[u] << 16), a0);
                a1 = fmaf(nr[u], __uint_as_float(v[u] & 0xffff0000u), a1);
            }
        }
    }
    float2 bb = *(const float2*)&bias[2 * lane];
    a0 = fmaxf(a0 + bb.x, 0.f);
    a1 = fmaxf(a1 + bb.y, 0.f);
    hout[(size_t)wid * 64 + lane] = f2bf(a0) | (f2bf(a1) << 16);
}

// ---------------- pooling: block(64) per graph (batch sorted); bf16 input ----------------

__global__ __launch_bounds__(64) void k_pool(const uint* __restrict__ h, const int* __restrict__ batch,
                                             float* __restrict__ pooled, int N) {
    int g = blockIdx.x;
    int t = threadIdx.x;
    int lo = 0, hi = N;
    while (lo < hi) { int mid = (lo + hi) >> 1; if (batch[mid] < g) lo = mid + 1; else hi = mid; }
    int s = lo;
    hi = N;
    while (lo < hi) { int mid = (lo + hi) >> 1; if (batch[mid] < g + 1) lo = mid + 1; else hi = mid; }
    int e = lo;
    float a0 = 0.f, a1 = 0.f;
    for (int n = s; n < e; ++n) {
        uint v = h[(size_t)n * 64 + t];
        a0 += __uint_as_float(v << 16);
        a1 += __uint_as_float(v & 0xffff0000u);
    }
    pooled[g * NFEAT + 2 * t]     = a0;
    pooled[g * NFEAT + 2 * t + 1] = a1;
}

// ---------------- head: out[g,c] = pooled[g,:] @ W_out[:,c] + b_out[c] (fp32 out) ----------------

__global__ __launch_bounds__(64) void k_head(const float* __restrict__ pooled, const float* __restrict__ Wout,
                                             const float* __restrict__ bout, float* __restrict__ out) {
    int g = blockIdx.x;
    int l = threadIdx.x;
    float p0 = pooled[g * NFEAT + l];
    float p1 = pooled[g * NFEAT + 64 + l];
#pragma unroll
    for (int c = 0; c < 10; ++c) {
        float v = fmaf(p0, Wout[l * 10 + c], p1 * Wout[(64 + l) * 10 + c]);
#pragma unroll
        for (int off = 32; off > 0; off >>= 1) v += __shfl_down(v, off);
        if (l == 0) out[g * 10 + c] = v + bout[c];
    }
}

// ---------------- launch ----------------

extern "C" void kernel_launch(void* const* d_in, const int* in_sizes, int n_in,
                              void* d_out, int out_size, void* d_ws, size_t ws_size,
                              hipStream_t stream) {
    const float* x         = (const float*)d_in[0];
    const void*  eidx_raw  = d_in[1];
    const void*  batch_raw = d_in[2];
    const float* W         = (const float*)d_in[3];
    const float* bias      = (const float*)d_in[4];
    const float* Wout      = (const float*)d_in[5];
    const float* bout      = (const float*)d_in[6];

    int N = in_sizes[0] / NFEAT;   // 50000
    int E = in_sizes[1] / 2;       // 800000
    int NG = out_size / 10;        // 512

    char* ws = (char*)d_ws;
    auto alloc = [&](size_t bytes) {
        char* p = ws;
        ws += (bytes + 255) & ~(size_t)255;
        return p;
    };
    uint*  hw      = (uint*)alloc((size_t)N * NFEAT * 2);   // bf16 activations
    uint*  hbuf    = (uint*)alloc((size_t)N * NFEAT * 2);   // bf16 activations
    int2*  csr     = (int2*)alloc((size_t)(E + N) * 8);
    int*   cnt     = (int*)alloc((size_t)N * 4);
    int*   pre     = (int*)alloc((size_t)N * 4);
    int*   bsum    = (int*)alloc(1024);
    int*   row_ptr = (int*)alloc((size_t)(N + 1) * 4);
    int*   cursor  = (int*)alloc((size_t)N * 4);
    float* dinv    = (float*)alloc((size_t)N * 4);
    float* pooled  = (float*)alloc((size_t)NG * NFEAT * 4);
    int*   eidx32  = (int*)alloc((size_t)2 * E * 4);
    int*   batch32 = (int*)alloc((size_t)N * 4);
    int*   flags   = (int*)alloc(256);

    // canonicalize possibly-int64 index inputs to int32
    k_detect<<<1, 256, 0, stream>>>((const int*)eidx_raw, 2 * E, &flags[0]);
    k_detect<<<1, 256, 0, stream>>>((const int*)batch_raw, N, &flags[1]);
    k_cvt<<<(2 * E + 255) / 256, 256, 0, stream>>>(eidx_raw, eidx32, 2 * E, &flags[0]);
    k_cvt<<<(N + 255) / 256, 256, 0, stream>>>(batch_raw, batch32, N, &flags[1]);

    int nbN = (N + 255) / 256;  // 196 <= 256 so scan2 single block works

    k_init_cnt<<<nbN, 256, 0, stream>>>(cnt, N);
    k_count<<<(E + 255) / 256, 256, 0, stream>>>(eidx32 + E, cnt, E);
    k_scan1<<<nbN, 256, 0, stream>>>(cnt, pre, bsum, N);
    k_scan2<<<1, 256, 0, stream>>>(bsum, nbN);
    k_scan3<<<nbN, 256, 0, stream>>>(cnt, pre, bsum, row_ptr, cursor, dinv, N, E + N);
    k_fill<<<(E + N + 255) / 256, 256, 0, stream>>>(eidx32, dinv, cursor, csr, E, N);

    for (int l = 0; l < 3; ++l) {
        const float* Wl = W + (size_t)l * NFEAT * NFEAT;
        if (l == 0)
            k_gemm<false><<<(N + 63) / 64, 256, 0, stream>>>(x, Wl, hw, N);
        else
            k_gemm<true><<<(N + 63) / 64, 256, 0, stream>>>(hbuf, Wl, hw, N);
        k_aggregate<<<(N * 64 + 255) / 256, 256, 0, stream>>>(hw, csr, row_ptr, bias + (size_t)l * NFEAT, hbuf, N);
    }

    k_pool<<<NG, 64, 0, stream>>>(hbuf, batch32, pooled, N);
    k_head<<<NG, 64, 0, stream>>>(pooled, Wout, bout, (float*)d_out);
}